// Round 1
// baseline (156.526 us; speedup 1.0000x reference)
//
#include <hip/hip_runtime.h>

#define NB 32
#define NN 2048
#define NC 16
#define ND 128
#define NH 128
#define NK 384
#define TM 64

typedef __bf16 bf16x8 __attribute__((ext_vector_type(8)));
typedef float f32x4 __attribute__((ext_vector_type(4)));

__device__ __forceinline__ unsigned short f2bf(float f){
  unsigned u = __float_as_uint(f);
  u = (u + 0x7fffu + ((u >> 16) & 1u)) >> 16;   // RNE
  return (unsigned short)u;
}
__device__ __forceinline__ unsigned enc_f32(float x){
  unsigned u = __float_as_uint(x);
  return (u & 0x80000000u) ? ~u : (u | 0x80000000u);
}
__device__ __forceinline__ float dec_f32(unsigned u){
  return __uint_as_float((u & 0x80000000u) ? (u & 0x7fffffffu) : ~u);
}

// store 8 bf16 (one 16B chunk) into swizzled wf LDS
__device__ __forceinline__ void st8(unsigned char* base, int row, int koff, const float* f){
  uint4 u;
  u.x = (unsigned)f2bf(f[0]) | ((unsigned)f2bf(f[1]) << 16);
  u.y = (unsigned)f2bf(f[2]) | ((unsigned)f2bf(f[3]) << 16);
  u.z = (unsigned)f2bf(f[4]) | ((unsigned)f2bf(f[5]) << 16);
  u.w = (unsigned)f2bf(f[6]) | ((unsigned)f2bf(f[7]) << 16);
  *(uint4*)(base + row*768 + (koff ^ ((row & 7) << 4))) = u;
}

// ---- prep: W1 (384x128 f32) -> bf16 fragments in exact B-frag lane order ----
// layout: [colfrag cf 0..7][kstep ks 0..11][lane 0..63] x 16B
// cf = w*2+f : col = (cf>>1)*32 + (cf&1)*16 + (lane&15); k = ks*32 + (lane>>4)*8 + j
__global__ __launch_bounds__(256) void prep_w1(const float* __restrict__ W1, uint4* __restrict__ w1frag){
  int tt = blockIdx.x * 256 + threadIdx.x;
  if (tt >= 8 * 12 * 64) return;
  int lane = tt & 63;
  int rest = tt >> 6;
  int ks = rest % 12;
  int cf = rest / 12;
  int col = (cf >> 1) * 32 + (cf & 1) * 16 + (lane & 15);
  int k0 = ks * 32 + (lane >> 4) * 8;
  unsigned ps[4];
  #pragma unroll
  for (int p = 0; p < 4; ++p){
    unsigned lo = f2bf(W1[(size_t)(k0 + 2*p) * NH + col]);
    unsigned hi = f2bf(W1[(size_t)(k0 + 2*p + 1) * NH + col]);
    ps[p] = lo | (hi << 16);
  }
  w1frag[tt] = make_uint4(ps[0], ps[1], ps[2], ps[3]);
}

// ---- main: gather + wf build (LDS) + bf16 MFMA GEMM + row-max + atomicMax ----
__global__ __launch_bounds__(256, 2) void tbcnn_main(
    const int* __restrict__ children, const float* __restrict__ nodeEmb,
    const uint4* __restrict__ w1frag, unsigned* __restrict__ pooled)
{
  __shared__ __align__(16) unsigned char wf_raw[TM * 768];
  // XCD-aware swizzle: 1024 blocks = 8 XCDs x 128; each XCD gets 4 consecutive batches
  const int j0 = ((blockIdx.x & 7) << 7) | (blockIdx.x >> 3);
  const int b    = j0 >> 5;
  const int tile = j0 & 31;
  const int n0 = tile * TM;
  const int t = threadIdx.x;
  const int lane = t & 63;
  const int w = t >> 6;

  // ---- gather phase: 4 threads per node, 32 dims each ----
  {
    const int nloc = t >> 2;
    const int q = t & 3;
    const int d0 = q * 32;
    const int gn = n0 + nloc;
    const float* embb = nodeEmb + (size_t)b * (NN * ND);
    const int* chp = children + ((size_t)b * NN + gn) * NC;
    int ci[NC];
    #pragma unroll
    for (int c = 0; c < NC; ++c) ci[c] = chp[c];
    int ns = 0;
    #pragma unroll
    for (int c = 0; c < NC; ++c) ns += (ci[c] > 0) ? 1 : 0;
    const float rdiv = 1.0f / (float)(((ns - 1) > 1) ? (ns - 1) : 1);
    float wr[NC], wl[NC];
    #pragma unroll
    for (int c = 0; c < NC; ++c){
      float mk = (ci[c] > 0) ? 1.0f : 0.0f;
      float r = (ns == 1) ? (0.5f * mk) : (mk * (float)c * rdiv);
      wr[c] = r;
      wl[c] = (1.0f - r) * mk;
    }
    // self vector -> k-block 0 (the "t" part of wf)
    const float* selfp = embb + (size_t)gn * ND;
    #pragma unroll
    for (int j = 0; j < 4; ++j){
      const int d = d0 + j * 8;
      float sv[8];
      float4 s0 = *(const float4*)(selfp + d);
      float4 s1 = *(const float4*)(selfp + d + 4);
      sv[0]=s0.x; sv[1]=s0.y; sv[2]=s0.z; sv[3]=s0.w;
      sv[4]=s1.x; sv[5]=s1.y; sv[6]=s1.z; sv[7]=s1.w;
      st8(wf_raw, nloc, 2 * d, sv);
    }
    // children weighted sums (r and l), each child row read exactly once
    float aR[32], aL[32];
    #pragma unroll
    for (int i = 0; i < 32; ++i){ aR[i] = 0.0f; aL[i] = 0.0f; }
    #pragma unroll
    for (int c = 0; c < NC; ++c){
      const float* cp = embb + (size_t)ci[c] * ND + d0;  // ci==0 -> weight 0, value irrelevant
      const float wrc = wr[c], wlc = wl[c];
      #pragma unroll
      for (int j = 0; j < 8; ++j){
        float4 u = *(const float4*)(cp + j * 4);
        aR[j*4+0] += wrc * u.x; aL[j*4+0] += wlc * u.x;
        aR[j*4+1] += wrc * u.y; aL[j*4+1] += wlc * u.y;
        aR[j*4+2] += wrc * u.z; aL[j*4+2] += wlc * u.z;
        aR[j*4+3] += wrc * u.w; aL[j*4+3] += wlc * u.w;
      }
    }
    #pragma unroll
    for (int j = 0; j < 4; ++j){
      const int d = d0 + j * 8;
      st8(wf_raw, nloc, 2 * (ND + d),     aR + j * 8);
      st8(wf_raw, nloc, 2 * (2 * ND + d), aL + j * 8);
    }
  }
  __syncthreads();

  // ---- B fragments: wave w covers cols [w*32, w*32+32), preloaded for all K ----
  bf16x8 Bfr[2][12];
  #pragma unroll
  for (int f = 0; f < 2; ++f)
    #pragma unroll
    for (int ks = 0; ks < 12; ++ks)
      Bfr[f][ks] = __builtin_bit_cast(bf16x8, w1frag[((w * 2 + f) * 12 + ks) * 64 + lane]);

  // ---- MFMA: 64 rows x 32 cols per wave, K=384 ----
  f32x4 acc[4][2];
  #pragma unroll
  for (int rf = 0; rf < 4; ++rf){
    acc[rf][0] = (f32x4){0.f, 0.f, 0.f, 0.f};
    acc[rf][1] = (f32x4){0.f, 0.f, 0.f, 0.f};
  }
  #pragma unroll
  for (int ks = 0; ks < 12; ++ks){
    bf16x8 a[4];
    const int koff = ks * 64 + ((lane >> 4) << 4);
    #pragma unroll
    for (int rf = 0; rf < 4; ++rf){
      const int row = rf * 16 + (lane & 15);
      a[rf] = __builtin_bit_cast(bf16x8,
                *(const uint4*)(wf_raw + row * 768 + (koff ^ ((row & 7) << 4))));
    }
    #pragma unroll
    for (int rf = 0; rf < 4; ++rf){
      acc[rf][0] = __builtin_amdgcn_mfma_f32_16x16x32_bf16(a[rf], Bfr[0][ks], acc[rf][0], 0, 0, 0);
      acc[rf][1] = __builtin_amdgcn_mfma_f32_16x16x32_bf16(a[rf], Bfr[1][ks], acc[rf][1], 0, 0, 0);
    }
  }

  // ---- max over the 64 rows (tanh deferred: monotonic), atomic pool ----
  float m0 = -3.0e38f, m1 = -3.0e38f;
  #pragma unroll
  for (int rf = 0; rf < 4; ++rf)
    #pragma unroll
    for (int i = 0; i < 4; ++i){
      m0 = fmaxf(m0, acc[rf][0][i]);
      m1 = fmaxf(m1, acc[rf][1][i]);
    }
  m0 = fmaxf(m0, __shfl_xor(m0, 16, 64));
  m0 = fmaxf(m0, __shfl_xor(m0, 32, 64));
  m1 = fmaxf(m1, __shfl_xor(m1, 16, 64));
  m1 = fmaxf(m1, __shfl_xor(m1, 32, 64));
  if (lane < 16){
    atomicMax(pooled + b * NH + w * 32 + lane,      enc_f32(m0));
    atomicMax(pooled + b * NH + w * 32 + 16 + lane, enc_f32(m1));
  }
}

// ---- final: tanh(pooled+b1) @ W2 + b2 -> tanh -> cosine(v1, v2) ----
__global__ __launch_bounds__(256) void tbcnn_final(
    const unsigned* __restrict__ pooled, const float* __restrict__ b1,
    const float* __restrict__ W2, const float* __restrict__ b2,
    float* __restrict__ out)
{
  __shared__ float hs[NB * NH];
  __shared__ float os[NB * NH];
  const int t = threadIdx.x;
  for (int i = t; i < NB * NH; i += 256){
    int col = i & 127;
    hs[i] = tanhf(dec_f32(pooled[i]) + b1[col]);
  }
  __syncthreads();
  for (int i = t; i < NB * NH; i += 256){
    int bb = i >> 7, o = i & 127;
    float s = b2[o];
    for (int k = 0; k < NH; ++k) s += hs[bb * NH + k] * W2[k * NH + o];
    os[i] = tanhf(s);
  }
  __syncthreads();
  if (t < 16){
    float s12 = 0.f, s11 = 0.f, s22 = 0.f;
    for (int d = 0; d < NH; ++d){
      float a = os[t * NH + d];
      float c = os[(t + 16) * NH + d];
      s12 += a * c; s11 += a * a; s22 += c * c;
    }
    float n1 = fmaxf(sqrtf(s11), 1e-8f);
    float n2 = fmaxf(sqrtf(s22), 1e-8f);
    out[t] = s12 / (n1 * n2);
  }
}

extern "C" void kernel_launch(void* const* d_in, const int* in_sizes, int n_in,
                              void* d_out, int out_size, void* d_ws, size_t ws_size,
                              hipStream_t stream)
{
  const int*   children = (const int*)d_in[0];
  const float* nodeEmb  = (const float*)d_in[1];
  const float* W1       = (const float*)d_in[2];
  const float* b1       = (const float*)d_in[3];
  const float* W2       = (const float*)d_in[4];
  const float* b2       = (const float*)d_in[5];
  float* out = (float*)d_out;

  unsigned* pooled = (unsigned*)d_ws;                         // 32*128*4 = 16 KB
  uint4* w1frag    = (uint4*)((char*)d_ws + NB * NH * 4);     // 96 KB

  hipMemsetAsync(pooled, 0, NB * NH * sizeof(unsigned), stream);  // enc-min (any real value wins)
  prep_w1<<<24, 256, 0, stream>>>(W1, w1frag);
  tbcnn_main<<<1024, 256, 0, stream>>>(children, nodeEmb, w1frag, pooled);
  tbcnn_final<<<1, 256, 0, stream>>>(pooled, b1, W2, b2, out);
}